// Round 6
// baseline (187.742 us; speedup 1.0000x reference)
//
#include <hip/hip_runtime.h>

// (B,P,C,H,W)=(256,10,32,8,8); Tm=19, Ta=10, hw=64. All I/O fp32.
// Horner: A_0=[F_0;1]; A_{p+1}=A_p*M_p+[F_{p+1};1] (p=0..8) -> A_9=[G;W]
// out[b,t,c,j] = (G[c,:].M_t[:,j]) / (W.M_t[:,j] + eps)
//
// R5 post-mortem: latency-bound (VALU 17%, HBM 16%, occ 18%): phase 1 ran on
// 2.25/8 waves behind 9 staged-barrier steps. v6: all 512 threads compute in
// phase 1 (1x4 tiles); M read straight from global (L1/L2-hot, no LDS staging,
// 1 barrier/iter); phase 2 = 20 barrier-free half-jobs over 8 waves.

#define EPSV 1e-6f
#define ATS  36   // At k-major row stride: At[k*36 + r], r=0..32; 16B-aligned quads

__global__ __launch_bounds__(512, 1) void k_fused(
    const float* __restrict__ feats,   // (256,10,32,64)
    const float* __restrict__ sim,     // (256,19,64,64)
    float* __restrict__ out)           // (2560,32,64)
{
    __shared__ __attribute__((aligned(16))) float At[2 * 64 * ATS];  // 18 KB ping-pong
    __shared__ __attribute__((aligned(16))) float wvec[512];

    const int tid  = threadIdx.x;
    const int lane = tid & 63;
    const int wave = tid >> 6;
    const int b    = blockIdx.x;

    const float* fb = feats + (size_t)b * 20480;   // 10*32*64
    const float* sb = sim   + (size_t)b * 77824;   // 19*64*64

    // ---- phase-1 worker coords: thread = (row r, col-quad j0); 32x16 grid ----
    const int r    = tid >> 4;          // 0..31
    const int j0   = (tid & 15) * 4;
    const bool xtra = (tid >= 496);     // wave 7 lanes 48..63 also own row 32
    const int jx   = (tid - 496) * 4;

    // init At[buf0] = [F_0 ; ones]^T
    {
        const float4 v = *(const float4*)&fb[r * 64 + j0];
        At[(j0 + 0) * ATS + r] = v.x;
        At[(j0 + 1) * ATS + r] = v.y;
        At[(j0 + 2) * ATS + r] = v.z;
        At[(j0 + 3) * ATS + r] = v.w;
        if (xtra) {
            At[(jx + 0) * ATS + 32] = 1.f;
            At[(jx + 1) * ATS + 32] = 1.f;
            At[(jx + 2) * ATS + 32] = 1.f;
            At[(jx + 3) * ATS + 32] = 1.f;
        }
    }
    __syncthreads();

    // ---- phase 1: 9 Horner steps, M/F straight from global ----
    for (int p = 0; p < 9; ++p) {
        const int cur = (p & 1) * (64 * ATS);
        const int nxt = ((p + 1) & 1) * (64 * ATS);
        const float* __restrict__ M = sb + p * 4096;
        const float* __restrict__ F = fb + (p + 1) * 2048;

        const float4 f = *(const float4*)&F[r * 64 + j0];

        float a0 = 0.f, a1 = 0.f, a2 = 0.f, a3 = 0.f;
        #pragma unroll 16
        for (int k = 0; k < 64; ++k) {
            const float  av = At[cur + k * ATS + r];            // broadcast b32
            const float4 m  = *(const float4*)&M[k * 64 + j0];  // global, L1/L2-hot
            a0 += av * m.x; a1 += av * m.y; a2 += av * m.z; a3 += av * m.w;
        }
        float e0 = 0.f, e1 = 0.f, e2 = 0.f, e3 = 0.f;
        if (xtra) {                       // weight row (r=32), seeded with ones
            #pragma unroll 16
            for (int k = 0; k < 64; ++k) {
                const float  av = At[cur + k * ATS + 32];
                const float4 m  = *(const float4*)&M[k * 64 + jx];
                e0 += av * m.x; e1 += av * m.y; e2 += av * m.z; e3 += av * m.w;
            }
        }

        At[nxt + (j0 + 0) * ATS + r] = a0 + f.x;
        At[nxt + (j0 + 1) * ATS + r] = a1 + f.y;
        At[nxt + (j0 + 2) * ATS + r] = a2 + f.z;
        At[nxt + (j0 + 3) * ATS + r] = a3 + f.w;
        if (xtra) {
            At[nxt + (jx + 0) * ATS + 32] = e0 + 1.f;
            At[nxt + (jx + 1) * ATS + 32] = e1 + 1.f;
            At[nxt + (jx + 2) * ATS + 32] = e2 + 1.f;
            At[nxt + (jx + 3) * ATS + 32] = e3 + 1.f;
        }
        __syncthreads();   // At[nxt] complete; At[cur] reads done
    }

    // ---- phase 2: [G;W]^T is in At buffer 1 (p=9 odd). 20 half-jobs, no barriers.
    // job = 2*t + h; wave w does jobs {w, w+8, (w+16 if w<4)}.
    const int G  = 64 * ATS;
    const int rg = lane >> 4;           // 0..3
    const int jj = (lane & 15) * 4;
    const int nj = (wave < 4) ? 3 : 2;

    for (int rd = 0; rd < nj; ++rd) {
        const int job = wave + 8 * rd;          // 0..19
        const int t   = job >> 1;
        const int h   = job & 1;
        const int r0  = h * 16 + rg * 4;        // 0..28
        const float* __restrict__ M = sb + (9 + t) * 4096;

        float acc[16];
        #pragma unroll
        for (int i = 0; i < 16; ++i) acc[i] = 0.f;
        float wv = 0.f;

        #pragma unroll 8
        for (int k = 0; k < 64; ++k) {
            const float4 a  = *(const float4*)&At[G + k * ATS + r0];  // 4-unique b128
            const float4 m  = *(const float4*)&M[k * 64 + jj];        // global
            const float  mw = M[k * 64 + lane];                       // coalesced b32
            const float  wk = At[G + k * ATS + 32];                   // broadcast
            wv += wk * mw;
            acc[0]  += a.x * m.x; acc[1]  += a.x * m.y; acc[2]  += a.x * m.z; acc[3]  += a.x * m.w;
            acc[4]  += a.y * m.x; acc[5]  += a.y * m.y; acc[6]  += a.y * m.z; acc[7]  += a.y * m.w;
            acc[8]  += a.z * m.x; acc[9]  += a.z * m.y; acc[10] += a.z * m.z; acc[11] += a.z * m.w;
            acc[12] += a.w * m.x; acc[13] += a.w * m.y; acc[14] += a.w * m.z; acc[15] += a.w * m.w;
        }

        // in-wave denominator exchange: lane holds wv for column `lane`
        wvec[wave * 64 + lane] = wv;
        const float4 wq = *(const float4*)&wvec[wave * 64 + jj];
        float4 rw;
        rw.x = 1.f / (wq.x + EPSV);
        rw.y = 1.f / (wq.y + EPSV);
        rw.z = 1.f / (wq.z + EPSV);
        rw.w = 1.f / (wq.w + EPSV);

        float* ob = out + ((size_t)b * 10 + t) * 2048;
        #pragma unroll
        for (int i = 0; i < 4; ++i) {
            float4 o;
            o.x = acc[i * 4 + 0] * rw.x;
            o.y = acc[i * 4 + 1] * rw.y;
            o.z = acc[i * 4 + 2] * rw.z;
            o.w = acc[i * 4 + 3] * rw.w;
            *(float4*)&ob[(r0 + i) * 64 + jj] = o;
        }
    }
}

extern "C" void kernel_launch(void* const* d_in, const int* in_sizes, int n_in,
                              void* d_out, int out_size, void* d_ws, size_t ws_size,
                              hipStream_t stream) {
    const float* feats = (const float*)d_in[0];
    const float* sim   = (const float*)d_in[1];
    k_fused<<<256, 512, 0, stream>>>(feats, sim, (float*)d_out);
}